// Round 4
// baseline (93.111 us; speedup 1.0000x reference)
//
#include <hip/hip_runtime.h>
#include <hip/hip_bf16.h>

typedef __bf16 bf16x8 __attribute__((ext_vector_type(8)));
typedef float  f32x4  __attribute__((ext_vector_type(4)));
typedef short  short8 __attribute__((ext_vector_type(8)));
typedef unsigned int u32;

#define KDE_IGNORE (-100)
#define NSL  16       // N slices (2 per XCD)
#define GBM  128      // m rows per block
#define GBN  64       // n cols per iteration
#define GD   256      // K (full depth, in registers for A)
#define NSLOT (NSL * 2)

__device__ __forceinline__ f32x4 mfma16x16(bf16x8 a, bf16x8 b, f32x4 c) {
  return __builtin_amdgcn_mfma_f32_16x16x32_bf16(a, b, c, 0, 0, 0);
}

// async 16B global->LDS (dest = wave-uniform base + lane*16)
__device__ __forceinline__ void gload_lds16(const short* g, short* l) {
  __builtin_amdgcn_global_load_lds(
      (const __attribute__((address_space(1))) u32*)g,
      (__attribute__((address_space(3))) u32*)l, 16, 0, 0);
}

// ---- Kernel 1: supp row norms (fp32 exact) + PRE-SWIZZLED bf16 copy.
// Row r's logical 16B chunk j is stored at position j ^ (r & 31).
template<bool CONV>
__global__ void supp_prep_kernel(const float* __restrict__ supp, float* __restrict__ sn,
                                 short* __restrict__ suppB, int N) {
  int row = blockIdx.x * 8 + ((threadIdx.x >> 6) << 1) + ((threadIdx.x & 63) >> 5);
  int c = threadIdx.x & 31;                 // logical 16B chunk (8 elems)
  const float* src = supp + (size_t)row * GD + c * 8;
  float4 a = *reinterpret_cast<const float4*>(src);
  float4 b = *reinterpret_cast<const float4*>(src + 4);
  if (CONV) {
    union { short8 v; __bf16 h[8]; } u;
    u.h[0] = (__bf16)a.x; u.h[1] = (__bf16)a.y; u.h[2] = (__bf16)a.z; u.h[3] = (__bf16)a.w;
    u.h[4] = (__bf16)b.x; u.h[5] = (__bf16)b.y; u.h[6] = (__bf16)b.z; u.h[7] = (__bf16)b.w;
    int pos = c ^ (row & 31);               // pre-swizzle for linear global_load_lds
    *reinterpret_cast<short8*>(suppB + (size_t)row * GD + pos * 8) = u.v;
  }
  float s = a.x*a.x + a.y*a.y + a.z*a.z + a.w*a.w
          + b.x*b.x + b.y*b.y + b.z*b.z + b.w*b.w;
#pragma unroll
  for (int off = 16; off >= 1; off >>= 1) s += __shfl_xor(s, off, 32);
  if (c == 0) sn[row] = s;
}

// ---- Kernel 2: fused GEMM + exp + masked row-accumulate, atomic-free.
// 256 thr = 4 waves (2m x 2n); wave tile 64m x 32n per iter, full K=256.
// A (pred) in registers for block lifetime; B double-buffered in LDS via
// global_load_lds from the pre-swizzled bf16 copy. Grid = (M/128)*16 = 512.
template<bool PRE>
__global__ __launch_bounds__(256, 2)
void kde_gemm_kernel(const float* __restrict__ pred, const float* __restrict__ suppF,
                     const short* __restrict__ suppB,
                     const int* __restrict__ tgt, const int* __restrict__ suppT,
                     const float* __restrict__ sn,
                     float* __restrict__ denomP, float* __restrict__ numerP,
                     int M, int N) {
  __shared__ __align__(16) short Bs[2][GBN * GD];   // 2 x 32 KiB

  const int bid = blockIdx.x;
  const int mb  = bid >> 4;           // 0..M/128-1
  const int s   = bid & 15;           // slice (bid%8 cycles XCDs)
  const int m0  = mb * GBM;
  const int nslice = N >> 4;          // 1024
  const int nbase  = s * nslice;
  const int niter  = nslice / GBN;    // 16
  const int t    = threadIdx.x;
  const int lane = t & 63;
  const int wid  = t >> 6;
  const int wm   = (wid >> 1) * 64;
  const int wnl  = (wid & 1) * 32;
  const int lr = lane >> 4, lc = lane & 15;

  // ---- A fragments: full K in registers (bf16), converted from fp32 once.
  bf16x8 af[4][8];
#pragma unroll
  for (int mt = 0; mt < 4; ++mt) {
    const float* base = pred + (size_t)(m0 + wm + mt * 16 + lc) * GD + lr * 8;
#pragma unroll
    for (int kk = 0; kk < 8; ++kk) {
      float4 a = *reinterpret_cast<const float4*>(base + kk * 32);
      float4 b = *reinterpret_cast<const float4*>(base + kk * 32 + 4);
      union { bf16x8 v; __bf16 h[8]; } u;
      u.h[0] = (__bf16)a.x; u.h[1] = (__bf16)a.y; u.h[2] = (__bf16)a.z; u.h[3] = (__bf16)a.w;
      u.h[4] = (__bf16)b.x; u.h[5] = (__bf16)b.y; u.h[6] = (__bf16)b.z; u.h[7] = (__bf16)b.w;
      af[mt][kk] = u.v;
    }
  }
  int tmv[4][4];
#pragma unroll
  for (int mt = 0; mt < 4; ++mt)
#pragma unroll
    for (int rg = 0; rg < 4; ++rg)
      tmv[mt][rg] = tgt[m0 + wm + mt * 16 + lr * 4 + rg];

  float dac[4][4] = {}, nac[4][4] = {};

  const float SC  = 1.4426950408889634f / 128.0f;   // log2e/128  (for 2*dot)
  const float SCH = 1.4426950408889634f / 256.0f;   // log2e/256  (for sn)

  // ---- stage tile 0 into buffer 0
  if (PRE) {
    const short* base = suppB + (size_t)nbase * GD;
#pragma unroll
    for (int i = 0; i < 8; ++i) {
      int ch = wid * 8 + i;                 // 1KB chunk of the 32KB tile
      gload_lds16(base + ch * 512 + lane * 8, &Bs[0][ch * 512]);
    }
  } else {
#pragma unroll
    for (int i = 0; i < 8; ++i) {
      int C = i * 256 + t; int row = C >> 5; int j = C & 31;
      const float* p = suppF + (size_t)(nbase + row) * GD + j * 8;
      float4 a = *reinterpret_cast<const float4*>(p);
      float4 b = *reinterpret_cast<const float4*>(p + 4);
      union { short8 v; __bf16 h[8]; } u;
      u.h[0] = (__bf16)a.x; u.h[1] = (__bf16)a.y; u.h[2] = (__bf16)a.z; u.h[3] = (__bf16)a.w;
      u.h[4] = (__bf16)b.x; u.h[5] = (__bf16)b.y; u.h[6] = (__bf16)b.z; u.h[7] = (__bf16)b.w;
      *reinterpret_cast<short8*>(&Bs[0][row * GD + ((j ^ (row & 31)) << 3)]) = u.v;
    }
  }
  __syncthreads();

  int cur = 0;
  for (int it = 0; it < niter; ++it) {
    const int n0 = nbase + it * GBN;
    const bool more = (it + 1 < niter);

    // issue next tile's staging early (lands at the end-of-iter barrier)
    short8 sreg[8];  // !PRE only
    if (more) {
      if (PRE) {
        const short* base = suppB + (size_t)(n0 + GBN) * GD;
#pragma unroll
        for (int i = 0; i < 8; ++i) {
          int ch = wid * 8 + i;
          gload_lds16(base + ch * 512 + lane * 8, &Bs[cur ^ 1][ch * 512]);
        }
      } else {
#pragma unroll
        for (int i = 0; i < 8; ++i) {
          int C = i * 256 + t; int row = C >> 5; int j = C & 31;
          const float* p = suppF + (size_t)(n0 + GBN + row) * GD + j * 8;
          float4 a = *reinterpret_cast<const float4*>(p);
          float4 b = *reinterpret_cast<const float4*>(p + 4);
          union { short8 v; __bf16 h[8]; } u;
          u.h[0] = (__bf16)a.x; u.h[1] = (__bf16)a.y; u.h[2] = (__bf16)a.z; u.h[3] = (__bf16)a.w;
          u.h[4] = (__bf16)b.x; u.h[5] = (__bf16)b.y; u.h[6] = (__bf16)b.z; u.h[7] = (__bf16)b.w;
          sreg[i] = u.v;
        }
      }
    }
    // per-iter epilogue metadata (latency hidden under MFMA)
    float snv[2]; int stv[2];
#pragma unroll
    for (int nt = 0; nt < 2; ++nt) {
      int j = n0 + wnl + nt * 16 + lc;
      snv[nt] = sn[j]; stv[nt] = suppT[j];
    }

    // MFMA over full K=256 (64 MFMAs/wave)
    f32x4 acc[4][2] = {};
    __builtin_amdgcn_s_setprio(1);
#pragma unroll
    for (int ks = 0; ks < 8; ++ks) {
      bf16x8 bfr[2];
#pragma unroll
      for (int nt = 0; nt < 2; ++nt) {
        int r = wnl + nt * 16 + lc;
        int cs = (ks * 4 + lr) ^ (r & 31);
        bfr[nt] = *reinterpret_cast<const bf16x8*>(&Bs[cur][r * GD + (cs << 3)]);
      }
#pragma unroll
      for (int mt = 0; mt < 4; ++mt)
#pragma unroll
        for (int nt = 0; nt < 2; ++nt)
          acc[mt][nt] = mfma16x16(af[mt][ks], bfr[nt], acc[mt][nt]);
    }
    __builtin_amdgcn_s_setprio(0);

    if (!PRE && more) {
#pragma unroll
      for (int i = 0; i < 8; ++i) {
        int C = i * 256 + t; int row = C >> 5; int j = C & 31;
        *reinterpret_cast<short8*>(&Bs[cur ^ 1][row * GD + ((j ^ (row & 31)) << 3)]) = sreg[i];
      }
    }

    // fused epilogue: e = 2^((2c - sn)*log2e/256); pn factor cancels in ratio
#pragma unroll
    for (int nt = 0; nt < 2; ++nt) {
      float sh = -snv[nt] * SCH;
#pragma unroll
      for (int mt = 0; mt < 4; ++mt)
#pragma unroll
        for (int rg = 0; rg < 4; ++rg) {
          float e = exp2f(fmaf(acc[mt][nt][rg], SC, sh));
          dac[mt][rg] += e;
          nac[mt][rg] += (stv[nt] == tmv[mt][rg]) ? e : 0.0f;
        }
    }
    __syncthreads();   // drains vmcnt(0): staged tile ready; buffers swap
    cur ^= 1;
  }

  // reduce over the 16 lanes (lc) sharing each m, write slot partials
#pragma unroll
  for (int off = 1; off < 16; off <<= 1) {
#pragma unroll
    for (int mt = 0; mt < 4; ++mt)
#pragma unroll
      for (int rg = 0; rg < 4; ++rg) {
        dac[mt][rg] += __shfl_xor(dac[mt][rg], off);
        nac[mt][rg] += __shfl_xor(nac[mt][rg], off);
      }
  }
  if (lc == 0) {
    const int slot = s * 2 + (wid & 1);     // 32 slots per m
#pragma unroll
    for (int mt = 0; mt < 4; ++mt)
#pragma unroll
      for (int rg = 0; rg < 4; ++rg) {
        int m = m0 + wm + mt * 16 + lr * 4 + rg;
        denomP[(size_t)slot * M + m] = dac[mt][rg];
        numerP[(size_t)slot * M + m] = nac[mt][rg];
      }
  }
}

// ---- Kernel 3: per-m sum over 32 slots -> nll, per-block partial sums
__global__ void kde_reduce_kernel(const float* __restrict__ denomP, const float* __restrict__ numerP,
                                  const int* __restrict__ tgt,
                                  float* __restrict__ bsum, float* __restrict__ bcnt, int M) {
  __shared__ float sS[4], sC[4];
  int m = blockIdx.x * 256 + threadIdx.x;
  float den = 0.0f, num = 0.0f;
#pragma unroll
  for (int sl = 0; sl < NSLOT; ++sl) {
    den += denomP[(size_t)sl * M + m];
    num += numerP[(size_t)sl * M + m];
  }
  int tg = tgt[m];
  bool valid = (tg != KDE_IGNORE);
  float p = fmaxf(num / fmaxf(den, 1e-10f), 1e-10f);
  float nll = valid ? -logf(p) : 0.0f;
  float cnt = valid ? 1.0f : 0.0f;
#pragma unroll
  for (int off = 32; off >= 1; off >>= 1) {
    nll += __shfl_xor(nll, off);
    cnt += __shfl_xor(cnt, off);
  }
  int wid = threadIdx.x >> 6, lane = threadIdx.x & 63;
  if (lane == 0) { sS[wid] = nll; sC[wid] = cnt; }
  __syncthreads();
  if (threadIdx.x == 0) {
    bsum[blockIdx.x] = sS[0] + sS[1] + sS[2] + sS[3];
    bcnt[blockIdx.x] = sC[0] + sC[1] + sC[2] + sC[3];
  }
}

__global__ void kde_final_kernel(const float* __restrict__ bsum, const float* __restrict__ bcnt,
                                 float* __restrict__ out, int nb) {
  int tid = threadIdx.x;
  float s = (tid < nb) ? bsum[tid] : 0.0f;
  float c = (tid < nb) ? bcnt[tid] : 0.0f;
#pragma unroll
  for (int off = 32; off >= 1; off >>= 1) {
    s += __shfl_xor(s, off);
    c += __shfl_xor(c, off);
  }
  if (tid == 0) out[0] = s / fmaxf(c, 1.0f);
}

extern "C" void kernel_launch(void* const* d_in, const int* in_sizes, int n_in,
                              void* d_out, int out_size, void* d_ws, size_t ws_size,
                              hipStream_t stream) {
  const float* supp  = (const float*)d_in[0];   // (N, 256)
  const float* pred  = (const float*)d_in[1];   // (M, 256)
  const int*   suppT = (const int*)d_in[2];     // (N,)
  const int*   tgt   = (const int*)d_in[3];     // (M,)
  const int N = in_sizes[2];
  const int M = in_sizes[3];

  float* sn     = (float*)d_ws;                      // N
  float* denomP = sn + N;                            // NSLOT*M
  float* numerP = denomP + (size_t)NSLOT * M;        // NSLOT*M
  float* bsum   = numerP + (size_t)NSLOT * M;        // M/256
  float* bcnt   = bsum + 16;                         // M/256
  short* suppB  = (short*)(bcnt + 16);               // N*256 bf16 (pre-swizzled)

  size_t small = sizeof(float) * ((size_t)N + 2 * (size_t)NSLOT * M + 32);
  bool pre = ws_size >= small + sizeof(short) * (size_t)N * GD;

  if (pre) supp_prep_kernel<true ><<<dim3(N / 8), dim3(256), 0, stream>>>(supp, sn, suppB, N);
  else     supp_prep_kernel<false><<<dim3(N / 8), dim3(256), 0, stream>>>(supp, sn, nullptr, N);

  dim3 grid((M / GBM) * NSL);   // 512 blocks; bid%8 cycles XCDs
  if (pre) kde_gemm_kernel<true ><<<grid, dim3(256), 0, stream>>>(
      pred, supp, suppB, tgt, suppT, sn, denomP, numerP, M, N);
  else     kde_gemm_kernel<false><<<grid, dim3(256), 0, stream>>>(
      pred, supp, suppB, tgt, suppT, sn, denomP, numerP, M, N);

  kde_reduce_kernel<<<dim3(M / 256), dim3(256), 0, stream>>>(denomP, numerP, tgt, bsum, bcnt, M);
  kde_final_kernel<<<dim3(1), dim3(64), 0, stream>>>(bsum, bcnt, (float*)d_out, M / 256);
}